// Round 4
// baseline (400.853 us; speedup 1.0000x reference)
//
#include <hip/hip_runtime.h>
#include <cstdint>
#include <cstddef>

typedef short v4s __attribute__((ext_vector_type(4)));
typedef short v8s __attribute__((ext_vector_type(8)));
typedef float v4f __attribute__((ext_vector_type(4)));

// fp32 -> bf16 round-to-nearest-even
__device__ __forceinline__ short f2bf(float f) {
    union { float f; unsigned u; } x; x.f = f;
    unsigned r = (x.u + 0x7FFFu + ((x.u >> 16) & 1u)) >> 16;
    return (short)(unsigned short)r;
}
__device__ __forceinline__ float bf2f(short h) {
    union { unsigned u; float f; } x; x.u = ((unsigned)(unsigned short)h) << 16;
    return x.f;
}

// async global->LDS, 16B per lane; LDS dest = wave-uniform base + lane*16
__device__ __forceinline__ void gld16(const void* g, void* l) {
    __builtin_amdgcn_global_load_lds((const __attribute__((address_space(1))) void*)g,
                                     (__attribute__((address_space(3))) void*)l, 16, 0, 0);
}

// ---------------------------------------------------------------- cvt fp32->bf16
__global__ __launch_bounds__(256) void cvt_bf16(
    const float* __restrict__ x, const float* __restrict__ wq, const float* __restrict__ wk,
    const float* __restrict__ wv, const float* __restrict__ wo,
    short* __restrict__ xb, short* __restrict__ wqb, short* __restrict__ wkb,
    short* __restrict__ wvb, short* __restrict__ wob)
{
    int bid = blockIdx.x;
    const float* src; short* dst; size_t base;
    if (bid < 4096)      { src = x;  dst = xb;  base = (size_t)bid * 1024; }
    else if (bid < 5120) { src = wq; dst = wqb; base = (size_t)(bid - 4096) * 1024; }
    else if (bid < 6144) { src = wk; dst = wkb; base = (size_t)(bid - 5120) * 1024; }
    else if (bid < 7168) { src = wv; dst = wvb; base = (size_t)(bid - 6144) * 1024; }
    else                 { src = wo; dst = wob; base = (size_t)(bid - 7168) * 1024; }
    size_t idx = base + (size_t)threadIdx.x * 4;
    v4f v = *(const v4f*)(src + idx);
    v4s o;
    o[0] = f2bf(v[0]); o[1] = f2bf(v[1]); o[2] = f2bf(v[2]); o[3] = f2bf(v[3]);
    *(v4s*)(dst + idx) = o;
}

// ---------------------------------------------------------------- QKV projection GEMM (round-2 proven)
// y = x @ W^T + b, M=4096 N=1024 K=1024, bf16 MFMA 16x16x32, 128x128 tiles, BK=32.
// mode z: 0=q (1/8-scaled, [b,h,l,dk]), 1=k ([b,h,l,dk]), 2=v transposed ([b,h,dk,l])
__global__ __launch_bounds__(256) void gemm_qkv(
    const short* __restrict__ xb,
    const short* __restrict__ wq, const short* __restrict__ wk, const short* __restrict__ wv,
    const float* __restrict__ bq, const float* __restrict__ bk, const float* __restrict__ bv,
    short* __restrict__ qo, short* __restrict__ ko, short* __restrict__ vto)
{
    __shared__ __align__(16) short At[128 * 32];
    __shared__ __align__(16) short Bt[128 * 32];
    const int K = 1024;
    const int mode = blockIdx.z;
    const short* W = (mode == 0) ? wq : (mode == 1) ? wk : wv;
    const float* bias = (mode == 0) ? bq : (mode == 1) ? bk : bv;
    const int m0 = blockIdx.y * 128, n0 = blockIdx.x * 128;
    const int tid = threadIdx.x, wave = tid >> 6, lane = tid & 63;
    const int quad = lane >> 4, ll = lane & 15;
    const int wr = wave >> 1, wc = wave & 1;
    const v4f zero4 = {0.f, 0.f, 0.f, 0.f};
    v4f acc[4][4];
    for (int i = 0; i < 4; ++i) for (int j = 0; j < 4; ++j) acc[i][j] = zero4;

    for (int k0 = 0; k0 < K; k0 += 32) {
        __syncthreads();
#pragma unroll
        for (int c = 0; c < 2; ++c) {
            int chb = (wave * 2 + c) * 64;
            int ch = chb + lane;
            int row = ch >> 2, col8 = (ch & 3) * 8;
            gld16(xb + (size_t)(m0 + row) * K + k0 + col8, &At[chb * 8]);
            gld16(W  + (size_t)(n0 + row) * K + k0 + col8, &Bt[chb * 8]);
        }
        __syncthreads();
        v8s af[4], bfr[4];
#pragma unroll
        for (int i = 0; i < 4; ++i) af[i]  = *(const v8s*)&At[(wr * 64 + i * 16 + ll) * 32 + quad * 8];
#pragma unroll
        for (int j = 0; j < 4; ++j) bfr[j] = *(const v8s*)&Bt[(wc * 64 + j * 16 + ll) * 32 + quad * 8];
#pragma unroll
        for (int i = 0; i < 4; ++i)
#pragma unroll
            for (int j = 0; j < 4; ++j)
                acc[i][j] = __builtin_amdgcn_mfma_f32_16x16x32_bf16(af[i], bfr[j], acc[i][j], 0, 0, 0);
    }

    const float scale = (mode == 0) ? 0.125f : 1.0f;
#pragma unroll
    for (int j = 0; j < 4; ++j) {
        int n = n0 + wc * 64 + j * 16 + ll;
        float bb = bias[n];
        int hh = n >> 6, dk = n & 63;
#pragma unroll
        for (int i = 0; i < 4; ++i) {
            int mbase = m0 + wr * 64 + i * 16 + quad * 4;
#pragma unroll
            for (int r = 0; r < 4; ++r) {
                int m = mbase + r;
                int b = m >> 10, li = m & 1023;
                short h = f2bf((acc[i][j][r] + bb) * scale);
                if (mode == 0)
                    qo[(((size_t)(b * 16 + hh) * 1024 + li) << 6) + dk] = h;
                else if (mode == 1)
                    ko[(((size_t)(b * 16 + hh) * 1024 + li) << 6) + dk] = h;
                else
                    vto[(((size_t)(b * 16 + hh) * 64 + dk) << 10) + li] = h;
            }
        }
    }
}

// ---------------------------------------------------------------- out projection GEMM (round-2 proven)
__global__ __launch_bounds__(256) void gemm_out(
    const short* __restrict__ A, const short* __restrict__ W,
    const float* __restrict__ bias, float* __restrict__ out)
{
    __shared__ __align__(16) short At[128 * 32];
    __shared__ __align__(16) short Bt[128 * 32];
    const int K = 1024;
    const int m0 = blockIdx.y * 128, n0 = blockIdx.x * 128;
    const int tid = threadIdx.x, wave = tid >> 6, lane = tid & 63;
    const int quad = lane >> 4, ll = lane & 15;
    const int wr = wave >> 1, wc = wave & 1;
    const v4f zero4 = {0.f, 0.f, 0.f, 0.f};
    v4f acc[4][4];
    for (int i = 0; i < 4; ++i) for (int j = 0; j < 4; ++j) acc[i][j] = zero4;

    for (int k0 = 0; k0 < K; k0 += 32) {
        __syncthreads();
#pragma unroll
        for (int c = 0; c < 2; ++c) {
            int chb = (wave * 2 + c) * 64;
            int ch = chb + lane;
            int row = ch >> 2, col8 = (ch & 3) * 8;
            gld16(A + (size_t)(m0 + row) * K + k0 + col8, &At[chb * 8]);
            gld16(W + (size_t)(n0 + row) * K + k0 + col8, &Bt[chb * 8]);
        }
        __syncthreads();
        v8s af[4], bfr[4];
#pragma unroll
        for (int i = 0; i < 4; ++i) af[i]  = *(const v8s*)&At[(wr * 64 + i * 16 + ll) * 32 + quad * 8];
#pragma unroll
        for (int j = 0; j < 4; ++j) bfr[j] = *(const v8s*)&Bt[(wc * 64 + j * 16 + ll) * 32 + quad * 8];
#pragma unroll
        for (int i = 0; i < 4; ++i)
#pragma unroll
            for (int j = 0; j < 4; ++j)
                acc[i][j] = __builtin_amdgcn_mfma_f32_16x16x32_bf16(af[i], bfr[j], acc[i][j], 0, 0, 0);
    }

#pragma unroll
    for (int j = 0; j < 4; ++j) {
        int n = n0 + wc * 64 + j * 16 + ll;
        float bb = bias[n];
#pragma unroll
        for (int i = 0; i < 4; ++i) {
            int mbase = m0 + wr * 64 + i * 16 + quad * 4;
#pragma unroll
            for (int r = 0; r < 4; ++r) {
                int m = mbase + r;
                out[(size_t)m * 1024 + n] = acc[i][j][r] + bb;
            }
        }
    }
}

// ---------------------------------------------------------------- fused attention (round-2) + column sums
// One block per (bh, 64-row q tile). Epilogue also accumulates per-column sums of the
// merged output into colsum[1024] via atomics (replaces col_part/col_mean kernels).
__global__ __launch_bounds__(256) void attn_flash(
    const short* __restrict__ qb, const short* __restrict__ kb, const short* __restrict__ vtb,
    float* __restrict__ merged, short* __restrict__ mergedh, float* __restrict__ colsum)
{
    __shared__ __align__(16) short Kt[64 * 64];   // [key j][dk], XOR-swizzled 16B granules
    __shared__ __align__(16) short Vt[64 * 64];   // [dk d][key j], XOR-swizzled
    __shared__ __align__(16) short Pt[4 * 16 * 68]; // per-wave P tile, stride 68
    const int bh = blockIdx.y, qt = blockIdx.x;
    const int tid = threadIdx.x, wave = tid >> 6, lane = tid & 63;
    const int quad = lane >> 4, ll = lane & 15;
    const short* qp = qb  + (size_t)bh * 1024 * 64;
    const short* kp = kb  + (size_t)bh * 1024 * 64;
    const short* vp = vtb + (size_t)bh * 64 * 1024;

    const int qrow = qt * 64 + wave * 16 + ll;
    v8s qa0 = *(const v8s*)(qp + (size_t)qrow * 64 + quad * 8);
    v8s qa1 = *(const v8s*)(qp + (size_t)qrow * 64 + 32 + quad * 8);

    const v4f zero4 = {0.f, 0.f, 0.f, 0.f};
    v4f oacc[4];
    for (int nt = 0; nt < 4; ++nt) oacc[nt] = zero4;
    float lsum[4] = {0.f, 0.f, 0.f, 0.f};
    short* pw = &Pt[wave * 16 * 68];

    for (int jt = 0; jt < 16; ++jt) {
        __syncthreads();
#pragma unroll
        for (int c = 0; c < 2; ++c) {
            int chb = (wave * 2 + c) * 64;
            int ch = chb + lane;
            int row = ch >> 3;
            int gi = ((ch & 7) ^ (row & 7)) * 8;
            gld16(kp + (size_t)(jt * 64 + row) * 64 + gi, &Kt[chb * 8]);
            gld16(vp + (size_t)row * 1024 + jt * 64 + gi, &Vt[chb * 8]);
        }
        __syncthreads();

        v4f sacc[4];
#pragma unroll
        for (int nt = 0; nt < 4; ++nt) {
            int n = nt * 16 + ll;
            int g0 = (quad ^ (n & 7)) * 8;
            int g1 = ((4 + quad) ^ (n & 7)) * 8;
            v8s b0 = *(const v8s*)&Kt[n * 64 + g0];
            v8s b1 = *(const v8s*)&Kt[n * 64 + g1];
            v4f s = zero4;
            s = __builtin_amdgcn_mfma_f32_16x16x32_bf16(qa0, b0, s, 0, 0, 0);
            s = __builtin_amdgcn_mfma_f32_16x16x32_bf16(qa1, b1, s, 0, 0, 0);
            sacc[nt] = s;
        }
#pragma unroll
        for (int nt = 0; nt < 4; ++nt) {
#pragma unroll
            for (int r = 0; r < 4; ++r) {
                float e = __expf(sacc[nt][r]);
                lsum[r] += e;
                pw[(quad * 4 + r) * 68 + nt * 16 + ll] = f2bf(e);
            }
        }
        __syncthreads();
        v4s p00 = *(const v4s*)&pw[ll * 68 + quad * 8];
        v4s p01 = *(const v4s*)&pw[ll * 68 + quad * 8 + 4];
        v4s p10 = *(const v4s*)&pw[ll * 68 + 32 + quad * 8];
        v4s p11 = *(const v4s*)&pw[ll * 68 + 32 + quad * 8 + 4];
        v8s pa0 = __builtin_shufflevector(p00, p01, 0, 1, 2, 3, 4, 5, 6, 7);
        v8s pa1 = __builtin_shufflevector(p10, p11, 0, 1, 2, 3, 4, 5, 6, 7);
#pragma unroll
        for (int nt = 0; nt < 4; ++nt) {
            int n = nt * 16 + ll;
            int g0 = (quad ^ (n & 7)) * 8;
            int g1 = ((4 + quad) ^ (n & 7)) * 8;
            v8s v0 = *(const v8s*)&Vt[n * 64 + g0];
            v8s v1 = *(const v8s*)&Vt[n * 64 + g1];
            oacc[nt] = __builtin_amdgcn_mfma_f32_16x16x32_bf16(pa0, v0, oacc[nt], 0, 0, 0);
            oacc[nt] = __builtin_amdgcn_mfma_f32_16x16x32_bf16(pa1, v1, oacc[nt], 0, 0, 0);
        }
    }

    float linv[4];
#pragma unroll
    for (int r = 0; r < 4; ++r) {
        float s = lsum[r];
        s += __shfl_xor(s, 1); s += __shfl_xor(s, 2);
        s += __shfl_xor(s, 4); s += __shfl_xor(s, 8);
        linv[r] = 1.0f / s;
    }
    const int b = bh >> 4, h = bh & 15;
    float csum[4] = {0.f, 0.f, 0.f, 0.f};
#pragma unroll
    for (int r = 0; r < 4; ++r) {
        int li = qt * 64 + wave * 16 + quad * 4 + r;
        size_t rowoff = ((size_t)(b * 1024 + li)) * 1024 + h * 64;
#pragma unroll
        for (int nt = 0; nt < 4; ++nt) {
            int d = nt * 16 + ll;
            float v = oacc[nt][r] * linv[r];
            merged[rowoff + d] = v;
            mergedh[rowoff + d] = f2bf(v);
            csum[nt] += v;
        }
    }
    // per-column partial sums: combine the 4 quads (rows) -> 16-row sums, one atomic per column/wave
#pragma unroll
    for (int nt = 0; nt < 4; ++nt) {
        csum[nt] += __shfl_xor(csum[nt], 16);
        csum[nt] += __shfl_xor(csum[nt], 32);
    }
    if (quad == 0) {
#pragma unroll
        for (int nt = 0; nt < 4; ++nt)
            atomicAdd(&colsum[h * 64 + nt * 16 + ll], csum[nt]);
    }
}

// ---------------------------------------------------------------- center + hi/lo split + transpose
// U = merged - colsum/4096 (per column); write Ut_hi/Ut_lo as [1024 d][4096 m] bf16
__global__ __launch_bounds__(256) void center_tr(
    const float* __restrict__ merged, const float* __restrict__ colsum,
    short* __restrict__ uth, short* __restrict__ utl)
{
    __shared__ short Hh[64][72];
    __shared__ short Hl[64][72];
    const int d0 = blockIdx.x * 64, m0 = blockIdx.y * 64;
    const int t = threadIdx.x;
    const int r0 = t >> 4, c4 = (t & 15) * 4;
    float mu[4];
#pragma unroll
    for (int e = 0; e < 4; ++e) mu[e] = colsum[d0 + c4 + e] * (1.0f / 4096.0f);
    for (int rr = 0; rr < 64; rr += 16) {
        int m = m0 + rr + r0;
        v4f v = *(const v4f*)(merged + (size_t)m * 1024 + d0 + c4);
#pragma unroll
        for (int e = 0; e < 4; ++e) {
            float u = v[e] - mu[e];
            short h = f2bf(u);
            Hh[c4 + e][rr + r0] = h;
            Hl[c4 + e][rr + r0] = f2bf(u - bf2f(h));
        }
    }
    __syncthreads();
    const int d = t >> 2, mg = (t & 3) * 16;
    v8s a0, a1, b0, b1;
#pragma unroll
    for (int e = 0; e < 8; ++e) {
        a0[e] = Hh[d][mg + e]; a1[e] = Hh[d][mg + 8 + e];
        b0[e] = Hl[d][mg + e]; b1[e] = Hl[d][mg + 8 + e];
    }
    size_t off = (size_t)(d0 + d) * 4096 + m0 + mg;
    *(v8s*)(uth + off) = a0; *(v8s*)(uth + off + 8) = a1;
    *(v8s*)(utl + off) = b0; *(v8s*)(utl + off + 8) = b1;
}

// ---------------------------------------------------------------- DeCov GEMM, split-K + fused reduction
// C = Ut @ Ut^T, K=4096 -> 8 chunks of 512. Grid (136 pairs, 8 chunks).
// Last block per pair reduces the pair's 8 partial tiles (deterministic order);
// last pair overall sums dsum[136] and writes the decov scalar.
__global__ __launch_bounds__(256) void gemm_decov(
    const short* __restrict__ uth, const short* __restrict__ utl, float* __restrict__ cpart,
    float* __restrict__ dsum, int* __restrict__ paircnt, int* __restrict__ gcnt,
    float* __restrict__ out)
{
    int p = blockIdx.x, I = 0, rem = p;
    while (rem >= 16 - I) { rem -= 16 - I; ++I; }
    const int J = I + rem;
    const int kbase = blockIdx.y * 512;
    __shared__ __align__(16) short Ah[64 * 32], Al[64 * 32], Bh[64 * 32], Bl[64 * 32];
    __shared__ float wsums[4];
    __shared__ int sflag;
    const int tid = threadIdx.x;
    const int wave = tid >> 6, lane = tid & 63;
    const int quad = lane >> 4, ll = lane & 15;
    const int wr = wave >> 1, wc = wave & 1;
    const v4f zero4 = {0.f, 0.f, 0.f, 0.f};
    v4f acc[2][2];
    for (int i = 0; i < 2; ++i) for (int j = 0; j < 2; ++j) acc[i][j] = zero4;

    for (int kk = 0; kk < 512; kk += 32) {
        int k0 = kbase + kk;
        __syncthreads();
        {
            int ch = wave * 64 + lane;
            int row = ch >> 2, col8 = (ch & 3) * 8;
            gld16(uth + (size_t)(I * 64 + row) * 4096 + k0 + col8, &Ah[wave * 512]);
            gld16(utl + (size_t)(I * 64 + row) * 4096 + k0 + col8, &Al[wave * 512]);
            gld16(uth + (size_t)(J * 64 + row) * 4096 + k0 + col8, &Bh[wave * 512]);
            gld16(utl + (size_t)(J * 64 + row) * 4096 + k0 + col8, &Bl[wave * 512]);
        }
        __syncthreads();
        v8s ah[2], al[2], bh[2], bl[2];
#pragma unroll
        for (int i = 0; i < 2; ++i) {
            int ro = (wr * 32 + i * 16 + ll) * 32 + quad * 8;
            ah[i] = *(const v8s*)&Ah[ro];
            al[i] = *(const v8s*)&Al[ro];
        }
#pragma unroll
        for (int j = 0; j < 2; ++j) {
            int ro = (wc * 32 + j * 16 + ll) * 32 + quad * 8;
            bh[j] = *(const v8s*)&Bh[ro];
            bl[j] = *(const v8s*)&Bl[ro];
        }
#pragma unroll
        for (int i = 0; i < 2; ++i)
#pragma unroll
            for (int j = 0; j < 2; ++j) {
                acc[i][j] = __builtin_amdgcn_mfma_f32_16x16x32_bf16(ah[i], bh[j], acc[i][j], 0, 0, 0);
                acc[i][j] = __builtin_amdgcn_mfma_f32_16x16x32_bf16(ah[i], bl[j], acc[i][j], 0, 0, 0);
                acc[i][j] = __builtin_amdgcn_mfma_f32_16x16x32_bf16(al[i], bh[j], acc[i][j], 0, 0, 0);
            }
    }

    float* dst = cpart + ((size_t)blockIdx.y * 136 + p) * 4096;
#pragma unroll
    for (int i = 0; i < 2; ++i)
#pragma unroll
        for (int j = 0; j < 2; ++j)
#pragma unroll
            for (int r = 0; r < 4; ++r) {
                int gi2 = wr * 32 + i * 16 + quad * 4 + r;
                int gj2 = wc * 32 + j * 16 + ll;
                dst[gi2 * 64 + gj2] = acc[i][j][r];
            }

    // ---- last-block-per-pair reduction
    __threadfence();                       // release this block's cpart writes
    if (tid == 0) sflag = atomicAdd(&paircnt[p], 1);
    __syncthreads();
    if (sflag != 7) return;                // not the last chunk for this pair
    __threadfence();                       // acquire other chunks' writes

    float s = 0.f;
    for (int e = tid; e < 4096; e += 256) {
        float c = 0.f;
#pragma unroll
        for (int kc = 0; kc < 8; ++kc) c += cpart[((size_t)kc * 136 + p) * 4096 + e];
        int gi = I * 64 + (e >> 6), gj = J * 64 + (e & 63);
        if (gi != gj) s += c * c;
    }
    if (I < J) s *= 2.f;
    s += __shfl_xor(s, 1); s += __shfl_xor(s, 2); s += __shfl_xor(s, 4);
    s += __shfl_xor(s, 8); s += __shfl_xor(s, 16); s += __shfl_xor(s, 32);
    if (lane == 0) wsums[wave] = s;
    __syncthreads();
    if (tid == 0) {
        dsum[p] = wsums[0] + wsums[1] + wsums[2] + wsums[3];
        __threadfence();                   // release dsum[p]
        sflag = atomicAdd(gcnt, 1);
    }
    __syncthreads();
    if (sflag != 135) return;              // not the last pair overall
    __threadfence();                       // acquire all dsum writes

    float t2 = (tid < 136) ? dsum[tid] : 0.f;
    t2 += __shfl_xor(t2, 1); t2 += __shfl_xor(t2, 2); t2 += __shfl_xor(t2, 4);
    t2 += __shfl_xor(t2, 8); t2 += __shfl_xor(t2, 16); t2 += __shfl_xor(t2, 32);
    if (lane == 0) wsums[wave] = t2;
    __syncthreads();
    if (tid == 0) {
        float tot = wsums[0] + wsums[1] + wsums[2] + wsums[3];
        // C = raw/4096; decov = 0.5 * sum_offdiag C^2
        out[4194304] = 0.5f * tot / (4096.0f * 4096.0f);
    }
}

// ---------------------------------------------------------------- launch
extern "C" void kernel_launch(void* const* d_in, const int* in_sizes, int n_in,
                              void* d_out, int out_size, void* d_ws, size_t ws_size,
                              hipStream_t stream) {
    const float* x  = (const float*)d_in[0];
    const float* Wq = (const float*)d_in[1];
    const float* bq = (const float*)d_in[2];
    const float* Wk = (const float*)d_in[3];
    const float* bk = (const float*)d_in[4];
    const float* Wv = (const float*)d_in[5];
    const float* bv = (const float*)d_in[6];
    const float* Wo = (const float*)d_in[7];
    const float* bo = (const float*)d_in[8];
    float* out = (float*)d_out;
    char* ws = (char*)d_ws;
    const size_t MB = 1ull << 20;
    short* xb      = (short*)(ws);              //  8 MB [4096][1024]
    short* wqb     = (short*)(ws + 8  * MB);    //  2 MB
    short* wkb     = (short*)(ws + 10 * MB);
    short* wvb     = (short*)(ws + 12 * MB);
    short* wob     = (short*)(ws + 14 * MB);
    short* qb      = (short*)(ws + 16 * MB);    //  8 MB [bh][l][dk] (q pre-scaled 1/8)
    short* kb      = (short*)(ws + 24 * MB);    //  8 MB [bh][l][dk]
    short* vtb     = (short*)(ws + 32 * MB);    //  8 MB [bh][dk][l]
    float* merged  = (float*)(ws + 40 * MB);    // 16 MB [4096][1024] fp32
    short* mergedh = (short*)(ws + 56 * MB);    //  8 MB bf16
    short* uth     = (short*)(ws + 65 * MB);    //  8 MB [1024][4096]
    short* utl     = (short*)(ws + 73 * MB);    //  8 MB
    // control block at ws+81MB: [0,544) dsum, [1024,1568) paircnt, [1568,1572) gcnt, [4096,8192) colsum
    char*  ctrl    = ws + 81 * MB;
    float* dsum    = (float*)(ctrl);
    int*   paircnt = (int*)(ctrl + 1024);
    int*   gcnt    = (int*)(ctrl + 1568);
    float* colsum  = (float*)(ctrl + 4096);
    float* cpart   = (float*)(ws);              // 17 MB [8][136][4096] (reuses dead xb/w/qb region)

    hipMemsetAsync(ctrl, 0, 8192, stream);      // zero dsum/counters/colsum (graph-safe)
    hipLaunchKernelGGL(cvt_bf16, dim3(8192), dim3(256), 0, stream,
                       x, Wq, Wk, Wv, Wo, xb, wqb, wkb, wvb, wob);
    hipLaunchKernelGGL(gemm_qkv, dim3(8, 32, 3), dim3(256), 0, stream,
                       xb, wqb, wkb, wvb, bq, bk, bv, qb, kb, vtb);
    hipLaunchKernelGGL(attn_flash, dim3(16, 64), dim3(256), 0, stream,
                       qb, kb, vtb, merged, mergedh, colsum);
    hipLaunchKernelGGL(gemm_out, dim3(8, 32), dim3(256), 0, stream,
                       mergedh, wob, bo, out);
    hipLaunchKernelGGL(center_tr, dim3(16, 64), dim3(256), 0, stream,
                       merged, colsum, uth, utl);
    hipLaunchKernelGGL(gemm_decov, dim3(136, 8), dim3(256), 0, stream,
                       uth, utl, cpart, dsum, paircnt, gcnt, out);
}

// Round 5
// 246.105 us; speedup vs baseline: 1.6288x; 1.6288x over previous
//
#include <hip/hip_runtime.h>
#include <cstdint>
#include <cstddef>

typedef short v4s __attribute__((ext_vector_type(4)));
typedef short v8s __attribute__((ext_vector_type(8)));
typedef float v4f __attribute__((ext_vector_type(4)));

// fp32 -> bf16 round-to-nearest-even
__device__ __forceinline__ short f2bf(float f) {
    union { float f; unsigned u; } x; x.f = f;
    unsigned r = (x.u + 0x7FFFu + ((x.u >> 16) & 1u)) >> 16;
    return (short)(unsigned short)r;
}
__device__ __forceinline__ float bf2f(short h) {
    union { unsigned u; float f; } x; x.u = ((unsigned)(unsigned short)h) << 16;
    return x.f;
}

// async global->LDS, 16B per lane; LDS dest = wave-uniform base + lane*16
__device__ __forceinline__ void gld16(const void* g, void* l) {
    __builtin_amdgcn_global_load_lds((const __attribute__((address_space(1))) void*)g,
                                     (__attribute__((address_space(3))) void*)l, 16, 0, 0);
}

// ---------------------------------------------------------------- cvt fp32->bf16
__global__ __launch_bounds__(256) void cvt_bf16(
    const float* __restrict__ x, const float* __restrict__ wq, const float* __restrict__ wk,
    const float* __restrict__ wv, const float* __restrict__ wo,
    short* __restrict__ xb, short* __restrict__ wqb, short* __restrict__ wkb,
    short* __restrict__ wvb, short* __restrict__ wob)
{
    int bid = blockIdx.x;
    const float* src; short* dst; size_t base;
    if (bid < 4096)      { src = x;  dst = xb;  base = (size_t)bid * 1024; }
    else if (bid < 5120) { src = wq; dst = wqb; base = (size_t)(bid - 4096) * 1024; }
    else if (bid < 6144) { src = wk; dst = wkb; base = (size_t)(bid - 5120) * 1024; }
    else if (bid < 7168) { src = wv; dst = wvb; base = (size_t)(bid - 6144) * 1024; }
    else                 { src = wo; dst = wob; base = (size_t)(bid - 7168) * 1024; }
    size_t idx = base + (size_t)threadIdx.x * 4;
    v4f v = *(const v4f*)(src + idx);
    v4s o;
    o[0] = f2bf(v[0]); o[1] = f2bf(v[1]); o[2] = f2bf(v[2]); o[3] = f2bf(v[3]);
    *(v4s*)(dst + idx) = o;
}

// ---------------------------------------------------------------- QKV projection GEMM (round-2 proven)
// y = x @ W^T + b, M=4096 N=1024 K=1024, bf16 MFMA 16x16x32, 128x128 tiles, BK=32.
// mode z: 0=q (1/8-scaled, [b,h,l,dk]), 1=k ([b,h,l,dk]), 2=v transposed ([b,h,dk,l])
__global__ __launch_bounds__(256) void gemm_qkv(
    const short* __restrict__ xb,
    const short* __restrict__ wq, const short* __restrict__ wk, const short* __restrict__ wv,
    const float* __restrict__ bq, const float* __restrict__ bk, const float* __restrict__ bv,
    short* __restrict__ qo, short* __restrict__ ko, short* __restrict__ vto)
{
    __shared__ __align__(16) short At[128 * 32];
    __shared__ __align__(16) short Bt[128 * 32];
    const int K = 1024;
    const int mode = blockIdx.z;
    const short* W = (mode == 0) ? wq : (mode == 1) ? wk : wv;
    const float* bias = (mode == 0) ? bq : (mode == 1) ? bk : bv;
    const int m0 = blockIdx.y * 128, n0 = blockIdx.x * 128;
    const int tid = threadIdx.x, wave = tid >> 6, lane = tid & 63;
    const int quad = lane >> 4, ll = lane & 15;
    const int wr = wave >> 1, wc = wave & 1;
    const v4f zero4 = {0.f, 0.f, 0.f, 0.f};
    v4f acc[4][4];
    for (int i = 0; i < 4; ++i) for (int j = 0; j < 4; ++j) acc[i][j] = zero4;

    for (int k0 = 0; k0 < K; k0 += 32) {
        __syncthreads();
#pragma unroll
        for (int c = 0; c < 2; ++c) {
            int chb = (wave * 2 + c) * 64;
            int ch = chb + lane;
            int row = ch >> 2, col8 = (ch & 3) * 8;
            gld16(xb + (size_t)(m0 + row) * K + k0 + col8, &At[chb * 8]);
            gld16(W  + (size_t)(n0 + row) * K + k0 + col8, &Bt[chb * 8]);
        }
        __syncthreads();
        v8s af[4], bfr[4];
#pragma unroll
        for (int i = 0; i < 4; ++i) af[i]  = *(const v8s*)&At[(wr * 64 + i * 16 + ll) * 32 + quad * 8];
#pragma unroll
        for (int j = 0; j < 4; ++j) bfr[j] = *(const v8s*)&Bt[(wc * 64 + j * 16 + ll) * 32 + quad * 8];
#pragma unroll
        for (int i = 0; i < 4; ++i)
#pragma unroll
            for (int j = 0; j < 4; ++j)
                acc[i][j] = __builtin_amdgcn_mfma_f32_16x16x32_bf16(af[i], bfr[j], acc[i][j], 0, 0, 0);
    }

    const float scale = (mode == 0) ? 0.125f : 1.0f;
#pragma unroll
    for (int j = 0; j < 4; ++j) {
        int n = n0 + wc * 64 + j * 16 + ll;
        float bb = bias[n];
        int hh = n >> 6, dk = n & 63;
#pragma unroll
        for (int i = 0; i < 4; ++i) {
            int mbase = m0 + wr * 64 + i * 16 + quad * 4;
#pragma unroll
            for (int r = 0; r < 4; ++r) {
                int m = mbase + r;
                int b = m >> 10, li = m & 1023;
                short h = f2bf((acc[i][j][r] + bb) * scale);
                if (mode == 0)
                    qo[(((size_t)(b * 16 + hh) * 1024 + li) << 6) + dk] = h;
                else if (mode == 1)
                    ko[(((size_t)(b * 16 + hh) * 1024 + li) << 6) + dk] = h;
                else
                    vto[(((size_t)(b * 16 + hh) * 64 + dk) << 10) + li] = h;
            }
        }
    }
}

// ---------------------------------------------------------------- out projection GEMM (round-2 proven)
__global__ __launch_bounds__(256) void gemm_out(
    const short* __restrict__ A, const short* __restrict__ W,
    const float* __restrict__ bias, float* __restrict__ out)
{
    __shared__ __align__(16) short At[128 * 32];
    __shared__ __align__(16) short Bt[128 * 32];
    const int K = 1024;
    const int m0 = blockIdx.y * 128, n0 = blockIdx.x * 128;
    const int tid = threadIdx.x, wave = tid >> 6, lane = tid & 63;
    const int quad = lane >> 4, ll = lane & 15;
    const int wr = wave >> 1, wc = wave & 1;
    const v4f zero4 = {0.f, 0.f, 0.f, 0.f};
    v4f acc[4][4];
    for (int i = 0; i < 4; ++i) for (int j = 0; j < 4; ++j) acc[i][j] = zero4;

    for (int k0 = 0; k0 < K; k0 += 32) {
        __syncthreads();
#pragma unroll
        for (int c = 0; c < 2; ++c) {
            int chb = (wave * 2 + c) * 64;
            int ch = chb + lane;
            int row = ch >> 2, col8 = (ch & 3) * 8;
            gld16(A + (size_t)(m0 + row) * K + k0 + col8, &At[chb * 8]);
            gld16(W + (size_t)(n0 + row) * K + k0 + col8, &Bt[chb * 8]);
        }
        __syncthreads();
        v8s af[4], bfr[4];
#pragma unroll
        for (int i = 0; i < 4; ++i) af[i]  = *(const v8s*)&At[(wr * 64 + i * 16 + ll) * 32 + quad * 8];
#pragma unroll
        for (int j = 0; j < 4; ++j) bfr[j] = *(const v8s*)&Bt[(wc * 64 + j * 16 + ll) * 32 + quad * 8];
#pragma unroll
        for (int i = 0; i < 4; ++i)
#pragma unroll
            for (int j = 0; j < 4; ++j)
                acc[i][j] = __builtin_amdgcn_mfma_f32_16x16x32_bf16(af[i], bfr[j], acc[i][j], 0, 0, 0);
    }

#pragma unroll
    for (int j = 0; j < 4; ++j) {
        int n = n0 + wc * 64 + j * 16 + ll;
        float bb = bias[n];
#pragma unroll
        for (int i = 0; i < 4; ++i) {
            int mbase = m0 + wr * 64 + i * 16 + quad * 4;
#pragma unroll
            for (int r = 0; r < 4; ++r) {
                int m = mbase + r;
                out[(size_t)m * 1024 + n] = acc[i][j][r] + bb;
            }
        }
    }
}

// ---------------------------------------------------------------- fused attention + column sums
// One block per (bh, 64-row q tile). Pt is WAVE-PRIVATE: no barrier needed between
// P-write and P-read (same-wave DS ops are in-order) -> 2 barriers/iter, not 3.
// Epilogue accumulates per-column sums of merged into colsum[1024] (atomics).
__global__ __launch_bounds__(256) void attn_flash(
    const short* __restrict__ qb, const short* __restrict__ kb, const short* __restrict__ vtb,
    float* __restrict__ merged, short* __restrict__ mergedh, float* __restrict__ colsum)
{
    __shared__ __align__(16) short Kt[64 * 64];   // [key j][dk], XOR-swizzled 16B granules
    __shared__ __align__(16) short Vt[64 * 64];   // [dk d][key j], XOR-swizzled
    __shared__ __align__(16) short Pt[4 * 16 * 68]; // per-wave P tile, stride 68
    const int bh = blockIdx.y, qt = blockIdx.x;
    const int tid = threadIdx.x, wave = tid >> 6, lane = tid & 63;
    const int quad = lane >> 4, ll = lane & 15;
    const short* qp = qb  + (size_t)bh * 1024 * 64;
    const short* kp = kb  + (size_t)bh * 1024 * 64;
    const short* vp = vtb + (size_t)bh * 64 * 1024;

    const int qrow = qt * 64 + wave * 16 + ll;
    v8s qa0 = *(const v8s*)(qp + (size_t)qrow * 64 + quad * 8);
    v8s qa1 = *(const v8s*)(qp + (size_t)qrow * 64 + 32 + quad * 8);

    const v4f zero4 = {0.f, 0.f, 0.f, 0.f};
    v4f oacc[4];
    for (int nt = 0; nt < 4; ++nt) oacc[nt] = zero4;
    float lsum[4] = {0.f, 0.f, 0.f, 0.f};
    short* pw = &Pt[wave * 16 * 68];

    for (int jt = 0; jt < 16; ++jt) {
        __syncthreads();
#pragma unroll
        for (int c = 0; c < 2; ++c) {
            int chb = (wave * 2 + c) * 64;
            int ch = chb + lane;
            int row = ch >> 3;
            int gi = ((ch & 7) ^ (row & 7)) * 8;
            gld16(kp + (size_t)(jt * 64 + row) * 64 + gi, &Kt[chb * 8]);
            gld16(vp + (size_t)row * 1024 + jt * 64 + gi, &Vt[chb * 8]);
        }
        __syncthreads();

        v4f sacc[4];
#pragma unroll
        for (int nt = 0; nt < 4; ++nt) {
            int n = nt * 16 + ll;
            int g0 = (quad ^ (n & 7)) * 8;
            int g1 = ((4 + quad) ^ (n & 7)) * 8;
            v8s b0 = *(const v8s*)&Kt[n * 64 + g0];
            v8s b1 = *(const v8s*)&Kt[n * 64 + g1];
            v4f s = zero4;
            s = __builtin_amdgcn_mfma_f32_16x16x32_bf16(qa0, b0, s, 0, 0, 0);
            s = __builtin_amdgcn_mfma_f32_16x16x32_bf16(qa1, b1, s, 0, 0, 0);
            sacc[nt] = s;
        }
#pragma unroll
        for (int nt = 0; nt < 4; ++nt) {
#pragma unroll
            for (int r = 0; r < 4; ++r) {
                float e = __expf(sacc[nt][r]);
                lsum[r] += e;
                pw[(quad * 4 + r) * 68 + nt * 16 + ll] = f2bf(e);
            }
        }
        // no __syncthreads: Pt is wave-private, DS ops are in-order within a wave
        v4s p00 = *(const v4s*)&pw[ll * 68 + quad * 8];
        v4s p01 = *(const v4s*)&pw[ll * 68 + quad * 8 + 4];
        v4s p10 = *(const v4s*)&pw[ll * 68 + 32 + quad * 8];
        v4s p11 = *(const v4s*)&pw[ll * 68 + 32 + quad * 8 + 4];
        v8s pa0 = __builtin_shufflevector(p00, p01, 0, 1, 2, 3, 4, 5, 6, 7);
        v8s pa1 = __builtin_shufflevector(p10, p11, 0, 1, 2, 3, 4, 5, 6, 7);
#pragma unroll
        for (int nt = 0; nt < 4; ++nt) {
            int n = nt * 16 + ll;
            int g0 = (quad ^ (n & 7)) * 8;
            int g1 = ((4 + quad) ^ (n & 7)) * 8;
            v8s v0 = *(const v8s*)&Vt[n * 64 + g0];
            v8s v1 = *(const v8s*)&Vt[n * 64 + g1];
            oacc[nt] = __builtin_amdgcn_mfma_f32_16x16x32_bf16(pa0, v0, oacc[nt], 0, 0, 0);
            oacc[nt] = __builtin_amdgcn_mfma_f32_16x16x32_bf16(pa1, v1, oacc[nt], 0, 0, 0);
        }
    }

    float linv[4];
#pragma unroll
    for (int r = 0; r < 4; ++r) {
        float s = lsum[r];
        s += __shfl_xor(s, 1); s += __shfl_xor(s, 2);
        s += __shfl_xor(s, 4); s += __shfl_xor(s, 8);
        linv[r] = 1.0f / s;
    }
    const int b = bh >> 4, h = bh & 15;
    float csum[4] = {0.f, 0.f, 0.f, 0.f};
#pragma unroll
    for (int r = 0; r < 4; ++r) {
        int li = qt * 64 + wave * 16 + quad * 4 + r;
        size_t rowoff = ((size_t)(b * 1024 + li)) * 1024 + h * 64;
#pragma unroll
        for (int nt = 0; nt < 4; ++nt) {
            int d = nt * 16 + ll;
            float v = oacc[nt][r] * linv[r];
            merged[rowoff + d] = v;
            mergedh[rowoff + d] = f2bf(v);
            csum[nt] += v;
        }
    }
    // per-column partials: combine quads -> 16-row sums, one atomic per column/wave
#pragma unroll
    for (int nt = 0; nt < 4; ++nt) {
        csum[nt] += __shfl_xor(csum[nt], 16);
        csum[nt] += __shfl_xor(csum[nt], 32);
    }
    if (quad == 0) {
#pragma unroll
        for (int nt = 0; nt < 4; ++nt)
            atomicAdd(&colsum[h * 64 + nt * 16 + ll], csum[nt]);
    }
}

// ---------------------------------------------------------------- center + hi/lo split + transpose
// U = merged - colsum/4096 (per column); write Ut_hi/Ut_lo as [1024 d][4096 m] bf16
__global__ __launch_bounds__(256) void center_tr(
    const float* __restrict__ merged, const float* __restrict__ colsum,
    short* __restrict__ uth, short* __restrict__ utl)
{
    __shared__ short Hh[64][72];
    __shared__ short Hl[64][72];
    const int d0 = blockIdx.x * 64, m0 = blockIdx.y * 64;
    const int t = threadIdx.x;
    const int r0 = t >> 4, c4 = (t & 15) * 4;
    float mu[4];
#pragma unroll
    for (int e = 0; e < 4; ++e) mu[e] = colsum[d0 + c4 + e] * (1.0f / 4096.0f);
    for (int rr = 0; rr < 64; rr += 16) {
        int m = m0 + rr + r0;
        v4f v = *(const v4f*)(merged + (size_t)m * 1024 + d0 + c4);
#pragma unroll
        for (int e = 0; e < 4; ++e) {
            float u = v[e] - mu[e];
            short h = f2bf(u);
            Hh[c4 + e][rr + r0] = h;
            Hl[c4 + e][rr + r0] = f2bf(u - bf2f(h));
        }
    }
    __syncthreads();
    const int d = t >> 2, mg = (t & 3) * 16;
    v8s a0, a1, b0, b1;
#pragma unroll
    for (int e = 0; e < 8; ++e) {
        a0[e] = Hh[d][mg + e]; a1[e] = Hh[d][mg + 8 + e];
        b0[e] = Hl[d][mg + e]; b1[e] = Hl[d][mg + 8 + e];
    }
    size_t off = (size_t)(d0 + d) * 4096 + m0 + mg;
    *(v8s*)(uth + off) = a0; *(v8s*)(uth + off + 8) = a1;
    *(v8s*)(utl + off) = b0; *(v8s*)(utl + off + 8) = b1;
}

// ---------------------------------------------------------------- DeCov GEMM, split-K (round-2 proven)
// C = Ut @ Ut^T, K=4096 -> 8 chunks of 512. Grid (136 pairs, 8 chunks). No fences:
// cross-block reduction happens in the separate decov_reduce launch.
__global__ __launch_bounds__(256) void gemm_decov(
    const short* __restrict__ uth, const short* __restrict__ utl, float* __restrict__ cpart)
{
    int p = blockIdx.x, I = 0, rem = p;
    while (rem >= 16 - I) { rem -= 16 - I; ++I; }
    const int J = I + rem;
    const int kbase = blockIdx.y * 512;
    __shared__ __align__(16) short Ah[64 * 32], Al[64 * 32], Bh[64 * 32], Bl[64 * 32];
    const int tid = threadIdx.x;
    const int wave = tid >> 6, lane = tid & 63;
    const int quad = lane >> 4, ll = lane & 15;
    const int wr = wave >> 1, wc = wave & 1;
    const v4f zero4 = {0.f, 0.f, 0.f, 0.f};
    v4f acc[2][2];
    for (int i = 0; i < 2; ++i) for (int j = 0; j < 2; ++j) acc[i][j] = zero4;

    for (int kk = 0; kk < 512; kk += 32) {
        int k0 = kbase + kk;
        __syncthreads();
        {
            int ch = wave * 64 + lane;
            int row = ch >> 2, col8 = (ch & 3) * 8;
            gld16(uth + (size_t)(I * 64 + row) * 4096 + k0 + col8, &Ah[wave * 512]);
            gld16(utl + (size_t)(I * 64 + row) * 4096 + k0 + col8, &Al[wave * 512]);
            gld16(uth + (size_t)(J * 64 + row) * 4096 + k0 + col8, &Bh[wave * 512]);
            gld16(utl + (size_t)(J * 64 + row) * 4096 + k0 + col8, &Bl[wave * 512]);
        }
        __syncthreads();
        v8s ah[2], al[2], bh[2], bl[2];
#pragma unroll
        for (int i = 0; i < 2; ++i) {
            int ro = (wr * 32 + i * 16 + ll) * 32 + quad * 8;
            ah[i] = *(const v8s*)&Ah[ro];
            al[i] = *(const v8s*)&Al[ro];
        }
#pragma unroll
        for (int j = 0; j < 2; ++j) {
            int ro = (wc * 32 + j * 16 + ll) * 32 + quad * 8;
            bh[j] = *(const v8s*)&Bh[ro];
            bl[j] = *(const v8s*)&Bl[ro];
        }
#pragma unroll
        for (int i = 0; i < 2; ++i)
#pragma unroll
            for (int j = 0; j < 2; ++j) {
                acc[i][j] = __builtin_amdgcn_mfma_f32_16x16x32_bf16(ah[i], bh[j], acc[i][j], 0, 0, 0);
                acc[i][j] = __builtin_amdgcn_mfma_f32_16x16x32_bf16(ah[i], bl[j], acc[i][j], 0, 0, 0);
                acc[i][j] = __builtin_amdgcn_mfma_f32_16x16x32_bf16(al[i], bh[j], acc[i][j], 0, 0, 0);
            }
    }

    float* dst = cpart + ((size_t)blockIdx.y * 136 + p) * 4096;
#pragma unroll
    for (int i = 0; i < 2; ++i)
#pragma unroll
        for (int j = 0; j < 2; ++j)
#pragma unroll
            for (int r = 0; r < 4; ++r) {
                int gi2 = wr * 32 + i * 16 + quad * 4 + r;
                int gj2 = wc * 32 + j * 16 + ll;
                dst[gi2 * 64 + gj2] = acc[i][j][r];
            }
}

// ---------------------------------------------------------------- DeCov reduce
__global__ __launch_bounds__(256) void decov_reduce(const float* __restrict__ cpart, float* __restrict__ dsum) {
    int p = blockIdx.x, I = 0, rem = p;
    while (rem >= 16 - I) { rem -= 16 - I; ++I; }
    const int J = I + rem;
    const int t = threadIdx.x;
    __shared__ float wsums[4];
    float s = 0.f;
    for (int e = t; e < 4096; e += 256) {
        float c = 0.f;
#pragma unroll
        for (int kc = 0; kc < 8; ++kc) c += cpart[((size_t)kc * 136 + p) * 4096 + e];
        int gi = I * 64 + (e >> 6), gj = J * 64 + (e & 63);
        if (gi != gj) s += c * c;
    }
    if (I < J) s *= 2.f;
    s += __shfl_xor(s, 1); s += __shfl_xor(s, 2); s += __shfl_xor(s, 4);
    s += __shfl_xor(s, 8); s += __shfl_xor(s, 16); s += __shfl_xor(s, 32);
    if ((t & 63) == 0) wsums[t >> 6] = s;
    __syncthreads();
    if (t == 0) dsum[p] = wsums[0] + wsums[1] + wsums[2] + wsums[3];
}

__global__ __launch_bounds__(256) void decov_final(const float* __restrict__ dsum, float* __restrict__ out) {
    const int t = threadIdx.x;
    __shared__ float wsums[4];
    float s = (t < 136) ? dsum[t] : 0.f;
    s += __shfl_xor(s, 1); s += __shfl_xor(s, 2); s += __shfl_xor(s, 4);
    s += __shfl_xor(s, 8); s += __shfl_xor(s, 16); s += __shfl_xor(s, 32);
    if ((t & 63) == 0) wsums[t >> 6] = s;
    __syncthreads();
    if (t == 0) {
        float tot = wsums[0] + wsums[1] + wsums[2] + wsums[3];
        // C = raw/4096; decov = 0.5 * sum_offdiag C^2
        out[4194304] = 0.5f * tot / (4096.0f * 4096.0f);
    }
}

// ---------------------------------------------------------------- launch
extern "C" void kernel_launch(void* const* d_in, const int* in_sizes, int n_in,
                              void* d_out, int out_size, void* d_ws, size_t ws_size,
                              hipStream_t stream) {
    const float* x  = (const float*)d_in[0];
    const float* Wq = (const float*)d_in[1];
    const float* bq = (const float*)d_in[2];
    const float* Wk = (const float*)d_in[3];
    const float* bk = (const float*)d_in[4];
    const float* Wv = (const float*)d_in[5];
    const float* bv = (const float*)d_in[6];
    const float* Wo = (const float*)d_in[7];
    const float* bo = (const float*)d_in[8];
    float* out = (float*)d_out;
    char* ws = (char*)d_ws;
    const size_t MB = 1ull << 20;
    short* xb      = (short*)(ws);              //  8 MB [4096][1024]
    short* wqb     = (short*)(ws + 8  * MB);    //  2 MB
    short* wkb     = (short*)(ws + 10 * MB);
    short* wvb     = (short*)(ws + 12 * MB);
    short* wob     = (short*)(ws + 14 * MB);
    short* qb      = (short*)(ws + 16 * MB);    //  8 MB [bh][l][dk] (q pre-scaled 1/8)
    short* kb      = (short*)(ws + 24 * MB);    //  8 MB [bh][l][dk]
    short* vtb     = (short*)(ws + 32 * MB);    //  8 MB [bh][dk][l]
    float* merged  = (float*)(ws + 40 * MB);    // 16 MB [4096][1024] fp32
    short* mergedh = (short*)(ws + 56 * MB);    //  8 MB bf16
    short* uth     = (short*)(ws + 65 * MB);    //  8 MB [1024][4096]
    short* utl     = (short*)(ws + 73 * MB);    //  8 MB
    float* dsum    = (float*)(ws + 81 * MB);    //  544 B
    float* colsum  = (float*)(ws + 81 * MB + 4096); // 4 KB
    float* cpart   = (float*)(ws);              // 17 MB [8][136][4096] (reuses dead region)

    hipMemsetAsync(colsum, 0, 4096, stream);    // zero colsum accumulators (graph-safe)
    hipLaunchKernelGGL(cvt_bf16, dim3(8192), dim3(256), 0, stream,
                       x, Wq, Wk, Wv, Wo, xb, wqb, wkb, wvb, wob);
    hipLaunchKernelGGL(gemm_qkv, dim3(8, 32, 3), dim3(256), 0, stream,
                       xb, wqb, wkb, wvb, bq, bk, bv, qb, kb, vtb);
    hipLaunchKernelGGL(attn_flash, dim3(16, 64), dim3(256), 0, stream,
                       qb, kb, vtb, merged, mergedh, colsum);
    hipLaunchKernelGGL(gemm_out, dim3(8, 32), dim3(256), 0, stream,
                       mergedh, wob, bo, out);
    hipLaunchKernelGGL(center_tr, dim3(16, 64), dim3(256), 0, stream,
                       merged, colsum, uth, utl);
    hipLaunchKernelGGL(gemm_decov, dim3(136, 8), dim3(256), 0, stream, uth, utl, cpart);
    hipLaunchKernelGGL(decov_reduce, dim3(136), dim3(256), 0, stream, cpart, dsum);
    hipLaunchKernelGGL(decov_final, dim3(1), dim3(256), 0, stream, dsum, out);
}

// Round 6
// 236.284 us; speedup vs baseline: 1.6965x; 1.0416x over previous
//
#include <hip/hip_runtime.h>
#include <cstdint>
#include <cstddef>

typedef short v4s __attribute__((ext_vector_type(4)));
typedef short v8s __attribute__((ext_vector_type(8)));
typedef float v4f __attribute__((ext_vector_type(4)));

// fp32 -> bf16 round-to-nearest-even
__device__ __forceinline__ short f2bf(float f) {
    union { float f; unsigned u; } x; x.f = f;
    unsigned r = (x.u + 0x7FFFu + ((x.u >> 16) & 1u)) >> 16;
    return (short)(unsigned short)r;
}
__device__ __forceinline__ float bf2f(short h) {
    union { unsigned u; float f; } x; x.u = ((unsigned)(unsigned short)h) << 16;
    return x.f;
}

// async global->LDS, 16B per lane; LDS dest = wave-uniform base + lane*16
__device__ __forceinline__ void gld16(const void* g, void* l) {
    __builtin_amdgcn_global_load_lds((const __attribute__((address_space(1))) void*)g,
                                     (__attribute__((address_space(3))) void*)l, 16, 0, 0);
}

// ---------------------------------------------------------------- cvt fp32->bf16 (+ colsum zero)
__global__ __launch_bounds__(256) void cvt_bf16(
    const float* __restrict__ x, const float* __restrict__ wq, const float* __restrict__ wk,
    const float* __restrict__ wv, const float* __restrict__ wo,
    short* __restrict__ xb, short* __restrict__ wqb, short* __restrict__ wkb,
    short* __restrict__ wvb, short* __restrict__ wob, float* __restrict__ colsum)
{
    int bid = blockIdx.x;
    const float* src; short* dst; size_t base;
    if (bid < 4096)      { src = x;  dst = xb;  base = (size_t)bid * 1024; }
    else if (bid < 5120) { src = wq; dst = wqb; base = (size_t)(bid - 4096) * 1024; }
    else if (bid < 6144) { src = wk; dst = wkb; base = (size_t)(bid - 5120) * 1024; }
    else if (bid < 7168) { src = wv; dst = wvb; base = (size_t)(bid - 6144) * 1024; }
    else                 { src = wo; dst = wob; base = (size_t)(bid - 7168) * 1024; }
    size_t idx = base + (size_t)threadIdx.x * 4;
    v4f v = *(const v4f*)(src + idx);
    v4s o;
    o[0] = f2bf(v[0]); o[1] = f2bf(v[1]); o[2] = f2bf(v[2]); o[3] = f2bf(v[3]);
    *(v4s*)(dst + idx) = o;
    if (bid == 0) {   // zero colsum accumulators (replaces hipMemsetAsync dispatch)
        v4f z = {0.f, 0.f, 0.f, 0.f};
        *(v4f*)(colsum + (size_t)threadIdx.x * 4) = z;
    }
}

// ---------------------------------------------------------------- QKV projection GEMM (round-2 proven)
// y = x @ W^T + b, M=4096 N=1024 K=1024, bf16 MFMA 16x16x32, 128x128 tiles, BK=32.
// mode z: 0=q (1/8-scaled, [b,h,l,dk]), 1=k ([b,h,l,dk]), 2=v transposed ([b,h,dk,l])
__global__ __launch_bounds__(256) void gemm_qkv(
    const short* __restrict__ xb,
    const short* __restrict__ wq, const short* __restrict__ wk, const short* __restrict__ wv,
    const float* __restrict__ bq, const float* __restrict__ bk, const float* __restrict__ bv,
    short* __restrict__ qo, short* __restrict__ ko, short* __restrict__ vto)
{
    __shared__ __align__(16) short At[128 * 32];
    __shared__ __align__(16) short Bt[128 * 32];
    const int K = 1024;
    const int mode = blockIdx.z;
    const short* W = (mode == 0) ? wq : (mode == 1) ? wk : wv;
    const float* bias = (mode == 0) ? bq : (mode == 1) ? bk : bv;
    const int m0 = blockIdx.y * 128, n0 = blockIdx.x * 128;
    const int tid = threadIdx.x, wave = tid >> 6, lane = tid & 63;
    const int quad = lane >> 4, ll = lane & 15;
    const int wr = wave >> 1, wc = wave & 1;
    const v4f zero4 = {0.f, 0.f, 0.f, 0.f};
    v4f acc[4][4];
    for (int i = 0; i < 4; ++i) for (int j = 0; j < 4; ++j) acc[i][j] = zero4;

    for (int k0 = 0; k0 < K; k0 += 32) {
        __syncthreads();
#pragma unroll
        for (int c = 0; c < 2; ++c) {
            int chb = (wave * 2 + c) * 64;
            int ch = chb + lane;
            int row = ch >> 2, col8 = (ch & 3) * 8;
            gld16(xb + (size_t)(m0 + row) * K + k0 + col8, &At[chb * 8]);
            gld16(W  + (size_t)(n0 + row) * K + k0 + col8, &Bt[chb * 8]);
        }
        __syncthreads();
        v8s af[4], bfr[4];
#pragma unroll
        for (int i = 0; i < 4; ++i) af[i]  = *(const v8s*)&At[(wr * 64 + i * 16 + ll) * 32 + quad * 8];
#pragma unroll
        for (int j = 0; j < 4; ++j) bfr[j] = *(const v8s*)&Bt[(wc * 64 + j * 16 + ll) * 32 + quad * 8];
#pragma unroll
        for (int i = 0; i < 4; ++i)
#pragma unroll
            for (int j = 0; j < 4; ++j)
                acc[i][j] = __builtin_amdgcn_mfma_f32_16x16x32_bf16(af[i], bfr[j], acc[i][j], 0, 0, 0);
    }

    const float scale = (mode == 0) ? 0.125f : 1.0f;
#pragma unroll
    for (int j = 0; j < 4; ++j) {
        int n = n0 + wc * 64 + j * 16 + ll;
        float bb = bias[n];
        int hh = n >> 6, dk = n & 63;
#pragma unroll
        for (int i = 0; i < 4; ++i) {
            int mbase = m0 + wr * 64 + i * 16 + quad * 4;
#pragma unroll
            for (int r = 0; r < 4; ++r) {
                int m = mbase + r;
                int b = m >> 10, li = m & 1023;
                short h = f2bf((acc[i][j][r] + bb) * scale);
                if (mode == 0)
                    qo[(((size_t)(b * 16 + hh) * 1024 + li) << 6) + dk] = h;
                else if (mode == 1)
                    ko[(((size_t)(b * 16 + hh) * 1024 + li) << 6) + dk] = h;
                else
                    vto[(((size_t)(b * 16 + hh) * 64 + dk) << 10) + li] = h;
            }
        }
    }
}

// ---------------------------------------------------------------- fused attention + column sums
// One block per (bh, 128-row q tile); 4 waves x 32 q-rows (2 m-subtiles). 64-key K/V tiles.
// Pt is WAVE-PRIVATE: no barrier between P-write and P-read -> 2 barriers/iter.
__global__ __launch_bounds__(256) void attn_flash(
    const short* __restrict__ qb, const short* __restrict__ kb, const short* __restrict__ vtb,
    float* __restrict__ merged, short* __restrict__ mergedh, float* __restrict__ colsum)
{
    __shared__ __align__(16) short Kt[64 * 64];     // [key j][dk], XOR-swizzled 16B granules
    __shared__ __align__(16) short Vt[64 * 64];     // [dk d][key j], XOR-swizzled
    __shared__ __align__(16) short Pt[4 * 32 * 68]; // per-wave 32x64 P tile, stride 68
    const int bh = blockIdx.y, qt = blockIdx.x;
    const int tid = threadIdx.x, wave = tid >> 6, lane = tid & 63;
    const int quad = lane >> 4, ll = lane & 15;
    const short* qp = qb  + (size_t)bh * 1024 * 64;
    const short* kp = kb  + (size_t)bh * 1024 * 64;
    const short* vp = vtb + (size_t)bh * 64 * 1024;

    v8s qa[2][2];
#pragma unroll
    for (int mi = 0; mi < 2; ++mi) {
        int qrow = qt * 128 + wave * 32 + mi * 16 + ll;
        qa[mi][0] = *(const v8s*)(qp + (size_t)qrow * 64 + quad * 8);
        qa[mi][1] = *(const v8s*)(qp + (size_t)qrow * 64 + 32 + quad * 8);
    }

    const v4f zero4 = {0.f, 0.f, 0.f, 0.f};
    v4f oacc[2][4];
    for (int mi = 0; mi < 2; ++mi) for (int nt = 0; nt < 4; ++nt) oacc[mi][nt] = zero4;
    float lsum[2][4];
    for (int mi = 0; mi < 2; ++mi) for (int r = 0; r < 4; ++r) lsum[mi][r] = 0.f;
    short* pw = &Pt[wave * 32 * 68];

    for (int jt = 0; jt < 16; ++jt) {
        __syncthreads();
#pragma unroll
        for (int c = 0; c < 2; ++c) {
            int chb = (wave * 2 + c) * 64;
            int ch = chb + lane;
            int row = ch >> 3;
            int gi = ((ch & 7) ^ (row & 7)) * 8;
            gld16(kp + (size_t)(jt * 64 + row) * 64 + gi, &Kt[chb * 8]);
            gld16(vp + (size_t)row * 1024 + jt * 64 + gi, &Vt[chb * 8]);
        }
        __syncthreads();

        v4f sacc[2][4];
#pragma unroll
        for (int nt = 0; nt < 4; ++nt) {
            int n = nt * 16 + ll;
            int g0 = (quad ^ (n & 7)) * 8;
            int g1 = ((4 + quad) ^ (n & 7)) * 8;
            v8s b0 = *(const v8s*)&Kt[n * 64 + g0];
            v8s b1 = *(const v8s*)&Kt[n * 64 + g1];
#pragma unroll
            for (int mi = 0; mi < 2; ++mi) {
                v4f s = zero4;
                s = __builtin_amdgcn_mfma_f32_16x16x32_bf16(qa[mi][0], b0, s, 0, 0, 0);
                s = __builtin_amdgcn_mfma_f32_16x16x32_bf16(qa[mi][1], b1, s, 0, 0, 0);
                sacc[mi][nt] = s;
            }
        }
#pragma unroll
        for (int mi = 0; mi < 2; ++mi)
#pragma unroll
            for (int nt = 0; nt < 4; ++nt)
#pragma unroll
                for (int r = 0; r < 4; ++r) {
                    float e = __expf(sacc[mi][nt][r]);
                    lsum[mi][r] += e;
                    pw[(mi * 16 + quad * 4 + r) * 68 + nt * 16 + ll] = f2bf(e);
                }
        // no __syncthreads: Pt is wave-private, DS ops are in-order within a wave
        v8s pa[2][2];
#pragma unroll
        for (int mi = 0; mi < 2; ++mi) {
            v4s p00 = *(const v4s*)&pw[(mi * 16 + ll) * 68 + quad * 8];
            v4s p01 = *(const v4s*)&pw[(mi * 16 + ll) * 68 + quad * 8 + 4];
            v4s p10 = *(const v4s*)&pw[(mi * 16 + ll) * 68 + 32 + quad * 8];
            v4s p11 = *(const v4s*)&pw[(mi * 16 + ll) * 68 + 32 + quad * 8 + 4];
            pa[mi][0] = __builtin_shufflevector(p00, p01, 0, 1, 2, 3, 4, 5, 6, 7);
            pa[mi][1] = __builtin_shufflevector(p10, p11, 0, 1, 2, 3, 4, 5, 6, 7);
        }
#pragma unroll
        for (int nt = 0; nt < 4; ++nt) {
            int n = nt * 16 + ll;
            int g0 = (quad ^ (n & 7)) * 8;
            int g1 = ((4 + quad) ^ (n & 7)) * 8;
            v8s v0 = *(const v8s*)&Vt[n * 64 + g0];
            v8s v1 = *(const v8s*)&Vt[n * 64 + g1];
#pragma unroll
            for (int mi = 0; mi < 2; ++mi) {
                oacc[mi][nt] = __builtin_amdgcn_mfma_f32_16x16x32_bf16(pa[mi][0], v0, oacc[mi][nt], 0, 0, 0);
                oacc[mi][nt] = __builtin_amdgcn_mfma_f32_16x16x32_bf16(pa[mi][1], v1, oacc[mi][nt], 0, 0, 0);
            }
        }
    }

    const int b = bh >> 4, h = bh & 15;
    float csum[4] = {0.f, 0.f, 0.f, 0.f};
#pragma unroll
    for (int mi = 0; mi < 2; ++mi) {
        float linv[4];
#pragma unroll
        for (int r = 0; r < 4; ++r) {
            float s = lsum[mi][r];
            s += __shfl_xor(s, 1); s += __shfl_xor(s, 2);
            s += __shfl_xor(s, 4); s += __shfl_xor(s, 8);
            linv[r] = 1.0f / s;
        }
#pragma unroll
        for (int r = 0; r < 4; ++r) {
            int li = qt * 128 + wave * 32 + mi * 16 + quad * 4 + r;
            size_t rowoff = ((size_t)(b * 1024 + li)) * 1024 + h * 64;
#pragma unroll
            for (int nt = 0; nt < 4; ++nt) {
                int d = nt * 16 + ll;
                float v = oacc[mi][nt][r] * linv[r];
                merged[rowoff + d] = v;
                mergedh[rowoff + d] = f2bf(v);
                csum[nt] += v;
            }
        }
    }
    // per-column partials: combine quads -> 32-row sums, one atomic per column/wave
#pragma unroll
    for (int nt = 0; nt < 4; ++nt) {
        csum[nt] += __shfl_xor(csum[nt], 16);
        csum[nt] += __shfl_xor(csum[nt], 32);
    }
    if (quad == 0) {
#pragma unroll
        for (int nt = 0; nt < 4; ++nt)
            atomicAdd(&colsum[h * 64 + nt * 16 + ll], csum[nt]);
    }
}

// ---------------------------------------------------------------- post-attn: out-proj GEMM + center/split/transpose
// blocks 0..255: out = mergedh @ Wo^T + bo (fp32). blocks 256..1279: center+transpose.
// Both depend only on attn and are mutually independent -> one dispatch.
__global__ __launch_bounds__(256) void post_attn(
    const short* __restrict__ A, const short* __restrict__ W, const float* __restrict__ bias,
    float* __restrict__ out,
    const float* __restrict__ merged, const float* __restrict__ colsum,
    short* __restrict__ uth, short* __restrict__ utl)
{
    __shared__ __align__(16) char smem[18432];
    const int bid = blockIdx.x;
    const int tid = threadIdx.x;
    if (bid < 256) {
        // ---------------- gemm_out body (round-2 proven), 128x128 tile
        short* At = (short*)smem;            // 128*32 shorts = 8 KB
        short* Bt = (short*)(smem + 8192);   // 8 KB
        const int K = 1024;
        const int n0 = (bid & 7) * 128, m0 = (bid >> 3) * 128;
        const int wave = tid >> 6, lane = tid & 63;
        const int quad = lane >> 4, ll = lane & 15;
        const int wr = wave >> 1, wc = wave & 1;
        const v4f zero4 = {0.f, 0.f, 0.f, 0.f};
        v4f acc[4][4];
        for (int i = 0; i < 4; ++i) for (int j = 0; j < 4; ++j) acc[i][j] = zero4;

        for (int k0 = 0; k0 < K; k0 += 32) {
            __syncthreads();
#pragma unroll
            for (int c = 0; c < 2; ++c) {
                int chb = (wave * 2 + c) * 64;
                int ch = chb + lane;
                int row = ch >> 2, col8 = (ch & 3) * 8;
                gld16(A + (size_t)(m0 + row) * K + k0 + col8, &At[chb * 8]);
                gld16(W + (size_t)(n0 + row) * K + k0 + col8, &Bt[chb * 8]);
            }
            __syncthreads();
            v8s af[4], bfr[4];
#pragma unroll
            for (int i = 0; i < 4; ++i) af[i]  = *(const v8s*)&At[(wr * 64 + i * 16 + ll) * 32 + quad * 8];
#pragma unroll
            for (int j = 0; j < 4; ++j) bfr[j] = *(const v8s*)&Bt[(wc * 64 + j * 16 + ll) * 32 + quad * 8];
#pragma unroll
            for (int i = 0; i < 4; ++i)
#pragma unroll
                for (int j = 0; j < 4; ++j)
                    acc[i][j] = __builtin_amdgcn_mfma_f32_16x16x32_bf16(af[i], bfr[j], acc[i][j], 0, 0, 0);
        }

#pragma unroll
        for (int j = 0; j < 4; ++j) {
            int n = n0 + wc * 64 + j * 16 + ll;
            float bb = bias[n];
#pragma unroll
            for (int i = 0; i < 4; ++i) {
                int mbase = m0 + wr * 64 + i * 16 + quad * 4;
#pragma unroll
                for (int r = 0; r < 4; ++r) {
                    int m = mbase + r;
                    out[(size_t)m * 1024 + n] = acc[i][j][r] + bb;
                }
            }
        }
    } else {
        // ---------------- center + hi/lo split + transpose body
        short (*Hh)[72] = (short(*)[72])smem;            // 64*72 shorts = 9216 B
        short (*Hl)[72] = (short(*)[72])(smem + 9216);   // 9216 B
        const int cid = bid - 256;
        const int d0 = (cid & 15) * 64, m0 = (cid >> 4) * 64;
        const int r0 = tid >> 4, c4 = (tid & 15) * 4;
        float mu[4];
#pragma unroll
        for (int e = 0; e < 4; ++e) mu[e] = colsum[d0 + c4 + e] * (1.0f / 4096.0f);
        for (int rr = 0; rr < 64; rr += 16) {
            int m = m0 + rr + r0;
            v4f v = *(const v4f*)(merged + (size_t)m * 1024 + d0 + c4);
#pragma unroll
            for (int e = 0; e < 4; ++e) {
                float u = v[e] - mu[e];
                short h = f2bf(u);
                Hh[c4 + e][rr + r0] = h;
                Hl[c4 + e][rr + r0] = f2bf(u - bf2f(h));
            }
        }
        __syncthreads();
        const int d = tid >> 2, mg = (tid & 3) * 16;
        v8s a0, a1, b0, b1;
#pragma unroll
        for (int e = 0; e < 8; ++e) {
            a0[e] = Hh[d][mg + e]; a1[e] = Hh[d][mg + 8 + e];
            b0[e] = Hl[d][mg + e]; b1[e] = Hl[d][mg + 8 + e];
        }
        size_t off = (size_t)(d0 + d) * 4096 + m0 + mg;
        *(v8s*)(uth + off) = a0; *(v8s*)(uth + off + 8) = a1;
        *(v8s*)(utl + off) = b0; *(v8s*)(utl + off + 8) = b1;
    }
}

// ---------------------------------------------------------------- DeCov GEMM, split-K (round-2 proven)
// C = Ut @ Ut^T, K=4096 -> 8 chunks of 512. Grid (136 pairs, 8 chunks). No fences.
__global__ __launch_bounds__(256) void gemm_decov(
    const short* __restrict__ uth, const short* __restrict__ utl, float* __restrict__ cpart)
{
    int p = blockIdx.x, I = 0, rem = p;
    while (rem >= 16 - I) { rem -= 16 - I; ++I; }
    const int J = I + rem;
    const int kbase = blockIdx.y * 512;
    __shared__ __align__(16) short Ah[64 * 32], Al[64 * 32], Bh[64 * 32], Bl[64 * 32];
    const int tid = threadIdx.x;
    const int wave = tid >> 6, lane = tid & 63;
    const int quad = lane >> 4, ll = lane & 15;
    const int wr = wave >> 1, wc = wave & 1;
    const v4f zero4 = {0.f, 0.f, 0.f, 0.f};
    v4f acc[2][2];
    for (int i = 0; i < 2; ++i) for (int j = 0; j < 2; ++j) acc[i][j] = zero4;

    for (int kk = 0; kk < 512; kk += 32) {
        int k0 = kbase + kk;
        __syncthreads();
        {
            int ch = wave * 64 + lane;
            int row = ch >> 2, col8 = (ch & 3) * 8;
            gld16(uth + (size_t)(I * 64 + row) * 4096 + k0 + col8, &Ah[wave * 512]);
            gld16(utl + (size_t)(I * 64 + row) * 4096 + k0 + col8, &Al[wave * 512]);
            gld16(uth + (size_t)(J * 64 + row) * 4096 + k0 + col8, &Bh[wave * 512]);
            gld16(utl + (size_t)(J * 64 + row) * 4096 + k0 + col8, &Bl[wave * 512]);
        }
        __syncthreads();
        v8s ah[2], al[2], bh[2], bl[2];
#pragma unroll
        for (int i = 0; i < 2; ++i) {
            int ro = (wr * 32 + i * 16 + ll) * 32 + quad * 8;
            ah[i] = *(const v8s*)&Ah[ro];
            al[i] = *(const v8s*)&Al[ro];
        }
#pragma unroll
        for (int j = 0; j < 2; ++j) {
            int ro = (wc * 32 + j * 16 + ll) * 32 + quad * 8;
            bh[j] = *(const v8s*)&Bh[ro];
            bl[j] = *(const v8s*)&Bl[ro];
        }
#pragma unroll
        for (int i = 0; i < 2; ++i)
#pragma unroll
            for (int j = 0; j < 2; ++j) {
                acc[i][j] = __builtin_amdgcn_mfma_f32_16x16x32_bf16(ah[i], bh[j], acc[i][j], 0, 0, 0);
                acc[i][j] = __builtin_amdgcn_mfma_f32_16x16x32_bf16(ah[i], bl[j], acc[i][j], 0, 0, 0);
                acc[i][j] = __builtin_amdgcn_mfma_f32_16x16x32_bf16(al[i], bh[j], acc[i][j], 0, 0, 0);
            }
    }

    float* dst = cpart + ((size_t)blockIdx.y * 136 + p) * 4096;
#pragma unroll
    for (int i = 0; i < 2; ++i)
#pragma unroll
        for (int j = 0; j < 2; ++j)
#pragma unroll
            for (int r = 0; r < 4; ++r) {
                int gi2 = wr * 32 + i * 16 + quad * 4 + r;
                int gj2 = wc * 32 + j * 16 + ll;
                dst[gi2 * 64 + gj2] = acc[i][j][r];
            }
}

// ---------------------------------------------------------------- DeCov reduce
__global__ __launch_bounds__(256) void decov_reduce(const float* __restrict__ cpart, float* __restrict__ dsum) {
    int p = blockIdx.x, I = 0, rem = p;
    while (rem >= 16 - I) { rem -= 16 - I; ++I; }
    const int J = I + rem;
    const int t = threadIdx.x;
    __shared__ float wsums[4];
    float s = 0.f;
    for (int e = t; e < 4096; e += 256) {
        float c = 0.f;
#pragma unroll
        for (int kc = 0; kc < 8; ++kc) c += cpart[((size_t)kc * 136 + p) * 4096 + e];
        int gi = I * 64 + (e >> 6), gj = J * 64 + (e & 63);
        if (gi != gj) s += c * c;
    }
    if (I < J) s *= 2.f;
    s += __shfl_xor(s, 1); s += __shfl_xor(s, 2); s += __shfl_xor(s, 4);
    s += __shfl_xor(s, 8); s += __shfl_xor(s, 16); s += __shfl_xor(s, 32);
    if ((t & 63) == 0) wsums[t >> 6] = s;
    __syncthreads();
    if (t == 0) dsum[p] = wsums[0] + wsums[1] + wsums[2] + wsums[3];
}

__global__ __launch_bounds__(256) void decov_final(const float* __restrict__ dsum, float* __restrict__ out) {
    const int t = threadIdx.x;
    __shared__ float wsums[4];
    float s = (t < 136) ? dsum[t] : 0.f;
    s += __shfl_xor(s, 1); s += __shfl_xor(s, 2); s += __shfl_xor(s, 4);
    s += __shfl_xor(s, 8); s += __shfl_xor(s, 16); s += __shfl_xor(s, 32);
    if ((t & 63) == 0) wsums[t >> 6] = s;
    __syncthreads();
    if (t == 0) {
        float tot = wsums[0] + wsums[1] + wsums[2] + wsums[3];
        // C = raw/4096; decov = 0.5 * sum_offdiag C^2
        out[4194304] = 0.5f * tot / (4096.0f * 4096.0f);
    }
}

// ---------------------------------------------------------------- launch
extern "C" void kernel_launch(void* const* d_in, const int* in_sizes, int n_in,
                              void* d_out, int out_size, void* d_ws, size_t ws_size,
                              hipStream_t stream) {
    const float* x  = (const float*)d_in[0];
    const float* Wq = (const float*)d_in[1];
    const float* bq = (const float*)d_in[2];
    const float* Wk = (const float*)d_in[3];
    const float* bk = (const float*)d_in[4];
    const float* Wv = (const float*)d_in[5];
    const float* bv = (const float*)d_in[6];
    const float* Wo = (const float*)d_in[7];
    const float* bo = (const float*)d_in[8];
    float* out = (float*)d_out;
    char* ws = (char*)d_ws;
    const size_t MB = 1ull << 20;
    short* xb      = (short*)(ws);              //  8 MB [4096][1024]
    short* wqb     = (short*)(ws + 8  * MB);    //  2 MB
    short* wkb     = (short*)(ws + 10 * MB);
    short* wvb     = (short*)(ws + 12 * MB);
    short* wob     = (short*)(ws + 14 * MB);
    short* qb      = (short*)(ws + 16 * MB);    //  8 MB [bh][l][dk] (q pre-scaled 1/8)
    short* kb      = (short*)(ws + 24 * MB);    //  8 MB [bh][l][dk]
    short* vtb     = (short*)(ws + 32 * MB);    //  8 MB [bh][dk][l]
    float* merged  = (float*)(ws + 40 * MB);    // 16 MB [4096][1024] fp32
    short* mergedh = (short*)(ws + 56 * MB);    //  8 MB bf16
    short* uth     = (short*)(ws + 65 * MB);    //  8 MB [1024][4096]
    short* utl     = (short*)(ws + 73 * MB);    //  8 MB
    float* dsum    = (float*)(ws + 81 * MB);    //  544 B
    float* colsum  = (float*)(ws + 81 * MB + 4096); // 4 KB
    float* cpart   = (float*)(ws);              // 17 MB [8][136][4096] (reuses dead region)

    hipLaunchKernelGGL(cvt_bf16, dim3(8192), dim3(256), 0, stream,
                       x, Wq, Wk, Wv, Wo, xb, wqb, wkb, wvb, wob, colsum);
    hipLaunchKernelGGL(gemm_qkv, dim3(8, 32, 3), dim3(256), 0, stream,
                       xb, wqb, wkb, wvb, bq, bk, bv, qb, kb, vtb);
    hipLaunchKernelGGL(attn_flash, dim3(8, 64), dim3(256), 0, stream,
                       qb, kb, vtb, merged, mergedh, colsum);
    hipLaunchKernelGGL(post_attn, dim3(1280), dim3(256), 0, stream,
                       mergedh, wob, bo, out, merged, colsum, uth, utl);
    hipLaunchKernelGGL(gemm_decov, dim3(136, 8), dim3(256), 0, stream, uth, utl, cpart);
    hipLaunchKernelGGL(decov_reduce, dim3(136), dim3(256), 0, stream, cpart, dsum);
    hipLaunchKernelGGL(decov_final, dim3(1), dim3(256), 0, stream, dsum, out);
}